// Round 1
// baseline (449.839 us; speedup 1.0000x reference)
//
#include <hip/hip_runtime.h>
#include <stdint.h>
#include <stddef.h>

// gcnmask: N=50000 nodes, DEG=16, F=128. Edges grouped by dst (dst = e/16) -> no atomics.
// Pipeline: pack(Wm,W -> bf16 MFMA-fragment order) ; main(mask GEMM + agg + support GEMM) ; final(adj-weighted gather).

#define NNODES 50000
#define DEG    16
#define FD     128
#define K2     256   // 2*F

typedef __bf16 bf16x8 __attribute__((ext_vector_type(8)));
typedef short  s16x8  __attribute__((ext_vector_type(8)));
typedef float  f32x4  __attribute__((ext_vector_type(4)));

__device__ __forceinline__ short f2bf_s(float f) {
    union { float f; uint32_t u; } v; v.f = f;
    uint32_t r = v.u + 0x7fffu + ((v.u >> 16) & 1u);   // RNE
    return (short)(r >> 16);
}

// Pack weights_mask [256x128] and weight [128x128] (row-major, fp32) into bf16
// B-operand fragment order for mfma_f32_16x16x32_bf16:
//   frag(kk,nt), lane l = q*16 + (n&15) with q=(k>>3)&3, element j = k&7.
//   packed index = ((kk*8+nt)*64 + l)*8 + j
__global__ void pack_weights_k(const float* __restrict__ wm, const float* __restrict__ w,
                               short* __restrict__ bpack, short* __restrict__ wpack) {
    int tid = blockIdx.x * blockDim.x + threadIdx.x;
    if (tid < K2 * FD) {
        int k = tid >> 7, n = tid & 127;
        int idx = (((k >> 5) * 8 + (n >> 4)) * 64 + ((k >> 3) & 3) * 16 + (n & 15)) * 8 + (k & 7);
        bpack[idx] = f2bf_s(wm[tid]);
    }
    if (tid < FD * FD) {
        int k = tid >> 7, n = tid & 127;
        int idx = (((k >> 5) * 8 + (n >> 4)) * 64 + ((k >> 3) & 3) * 16 + (n & 15)) * 8 + (k & 7);
        wpack[idx] = f2bf_s(w[tid]);
    }
}

// Block = 256 threads = 4 waves = 16 nodes (wave w -> nodes node0+4w .. +3).
// Phase 1: mask GEMM. A[e][k] = k<128 ? x[dst(e)][k] : x[src(e)][k-128], gathered to regs.
//          Wm fragments in 64KB LDS. Per wave: 4 Mtiles x 8 Ntiles x 8 Ksteps = 256 MFMAs.
// Phase 2: sigmoid + agg (shuffle-reduce over quads) -> x_new into LDS (aliased over Blds).
// Phase 3: support = x_new[16x128] @ weight via MFMA, weight frags from global (packed).
__global__ __launch_bounds__(256) void mask_agg_support_k(
    const float* __restrict__ x, const int* __restrict__ esrc,
    const short* __restrict__ bpack, const short* __restrict__ wpack,
    float* __restrict__ support)
{
    __shared__ short Blds[K2 * FD];                 // 64 KB
    float* xn = reinterpret_cast<float*>(Blds);     // aliased after phase-1 barrier; row stride 132 (pad vs 16-way bank conflict)

    const int tid   = threadIdx.x;
    const int wave  = tid >> 6;
    const int lane  = tid & 63;
    const int q     = lane >> 4;                    // quad
    const int m     = lane & 15;
    const int node0 = blockIdx.x * 16;
    const int wn0   = node0 + wave * 4;

    // stage packed Wm fragments into LDS (4096 uint4 / 256 threads = 16 iters)
    {
        const uint4* s = reinterpret_cast<const uint4*>(bpack);
        uint4* d = reinterpret_cast<uint4*>(Blds);
        #pragma unroll
        for (int i = 0; i < 16; ++i) d[tid + 256 * i] = s[tid + 256 * i];
    }

    int srcid[4];
    #pragma unroll
    for (int mt = 0; mt < 4; ++mt) srcid[mt] = esrc[(wn0 + mt) * DEG + m];

    __syncthreads();

    f32x4 acc[4][8];
    #pragma unroll
    for (int mt = 0; mt < 4; ++mt)
        #pragma unroll
        for (int nt = 0; nt < 8; ++nt)
            acc[mt][nt] = (f32x4){0.f, 0.f, 0.f, 0.f};

    #pragma unroll
    for (int kk = 0; kk < 8; ++kk) {
        bf16x8 af[4];
        #pragma unroll
        for (int mt = 0; mt < 4; ++mt) {
            // A-operand layout: row = m, k = kk*32 + q*8 + j
            const float* row = (kk < 4)
                ? (x + (size_t)(wn0 + mt) * FD + (kk * 32 + q * 8))          // center: wave-uniform per quad
                : (x + (size_t)srcid[mt] * FD + ((kk - 4) * 32 + q * 8));    // neighbor gather, 32B/lane
            f32x4 lo = *reinterpret_cast<const f32x4*>(row);
            f32x4 hi = *reinterpret_cast<const f32x4*>(row + 4);
            bf16x8 a;
            a[0]=(__bf16)lo.x; a[1]=(__bf16)lo.y; a[2]=(__bf16)lo.z; a[3]=(__bf16)lo.w;
            a[4]=(__bf16)hi.x; a[5]=(__bf16)hi.y; a[6]=(__bf16)hi.z; a[7]=(__bf16)hi.w;
            af[mt] = a;
        }
        #pragma unroll
        for (int nt = 0; nt < 8; ++nt) {
            s16x8 braw = *reinterpret_cast<const s16x8*>(Blds + ((size_t)(kk * 8 + nt) * 64 + lane) * 8);
            bf16x8 bfr = __builtin_bit_cast(bf16x8, braw);
            #pragma unroll
            for (int mt = 0; mt < 4; ++mt)
                acc[mt][nt] = __builtin_amdgcn_mfma_f32_16x16x32_bf16(af[mt], bfr, acc[mt][nt], 0, 0, 0);
        }
    }

    __syncthreads();   // all waves done reading Blds; safe to overwrite with x_new

    // Phase 2: C/D layout: col = lane&15 (feature within Ntile), row = q*4 + i (edge within node)
    #pragma unroll
    for (int mt = 0; mt < 4; ++mt) {
        const int node = wn0 + mt;
        const int eb = node * DEG + q * 4;
        const int s0 = esrc[eb], s1 = esrc[eb + 1], s2 = esrc[eb + 2], s3 = esrc[eb + 3];
        #pragma unroll
        for (int nt = 0; nt < 8; ++nt) {
            const int f = nt * 16 + m;
            f32x4 z = acc[mt][nt];
            float g0 = 1.f / (1.f + __expf(-z.x));
            float g1 = 1.f / (1.f + __expf(-z.y));
            float g2 = 1.f / (1.f + __expf(-z.z));
            float g3 = 1.f / (1.f + __expf(-z.w));
            float p = g0 * x[(size_t)s0 * FD + f]
                    + g1 * x[(size_t)s1 * FD + f]
                    + g2 * x[(size_t)s2 * FD + f]
                    + g3 * x[(size_t)s3 * FD + f];
            p += __shfl_xor(p, 16);
            p += __shfl_xor(p, 32);
            if (q == 0) xn[(wave * 4 + mt) * 132 + f] = x[(size_t)node * FD + f] + p;
        }
    }
    __syncthreads();

    // Phase 3: support[16 x 128] = x_new @ weight. Wave handles nt = 2*wave, 2*wave+1.
    f32x4 sacc[2];
    sacc[0] = (f32x4){0.f, 0.f, 0.f, 0.f};
    sacc[1] = (f32x4){0.f, 0.f, 0.f, 0.f};
    #pragma unroll
    for (int kk = 0; kk < 4; ++kk) {
        const float* p = &xn[m * 132 + kk * 32 + q * 8];
        bf16x8 a;
        a[0]=(__bf16)p[0]; a[1]=(__bf16)p[1]; a[2]=(__bf16)p[2]; a[3]=(__bf16)p[3];
        a[4]=(__bf16)p[4]; a[5]=(__bf16)p[5]; a[6]=(__bf16)p[6]; a[7]=(__bf16)p[7];
        #pragma unroll
        for (int t = 0; t < 2; ++t) {
            const int nt = wave * 2 + t;
            s16x8 braw = *reinterpret_cast<const s16x8*>(wpack + ((size_t)(kk * 8 + nt) * 64 + lane) * 8);
            sacc[t] = __builtin_amdgcn_mfma_f32_16x16x32_bf16(a, __builtin_bit_cast(bf16x8, braw), sacc[t], 0, 0, 0);
        }
    }
    #pragma unroll
    for (int t = 0; t < 2; ++t) {
        const int nt = wave * 2 + t;
        #pragma unroll
        for (int i = 0; i < 4; ++i)
            support[(size_t)(node0 + q * 4 + i) * FD + nt * 16 + m] = sacc[t][i];
    }
}

// out[n][f] = bias[f] + sum_d adj[n*16+d] * support[src[n*16+d]][f]
__global__ __launch_bounds__(256) void final_agg_k(
    const float* __restrict__ support, const float* __restrict__ adj,
    const int* __restrict__ esrc, const float* __restrict__ bias,
    float* __restrict__ out)
{
    int tid = blockIdx.x * 256 + threadIdx.x;
    int n = tid >> 7;
    int f = tid & 127;
    float a = bias[f];
    int eb = n * DEG;
    #pragma unroll
    for (int d = 0; d < DEG; ++d) {
        int s = esrc[eb + d];
        a += adj[eb + d] * support[(size_t)s * FD + f];
    }
    out[tid] = a;
}

extern "C" void kernel_launch(void* const* d_in, const int* in_sizes, int n_in,
                              void* d_out, int out_size, void* d_ws, size_t ws_size,
                              hipStream_t stream) {
    const float* x      = (const float*)d_in[0];
    const float* weight = (const float*)d_in[1];
    const float* bias   = (const float*)d_in[2];
    const float* wm     = (const float*)d_in[3];
    const float* adj    = (const float*)d_in[4];
    const int*   esrc   = (const int*)d_in[5];
    // d_in[6] edge_dst unused: dst(e) = e/16 by construction.

    // ws layout: [0,64K) Wm packed bf16 | [64K,96K) weight packed bf16 | [96K, 96K+25.6MB) support fp32
    short* bpack   = (short*)d_ws;
    short* wpack   = (short*)((char*)d_ws + 65536);
    float* support = (float*)((char*)d_ws + 65536 + 32768);
    float* out     = (float*)d_out;

    pack_weights_k<<<128, 256, 0, stream>>>(wm, weight, bpack, wpack);
    mask_agg_support_k<<<NNODES / 16, 256, 0, stream>>>(x, esrc, bpack, wpack, support);
    final_agg_k<<<(NNODES * FD) / 256, 256, 0, stream>>>(support, adj, esrc, bias, out);
}

// Round 2
// 282.421 us; speedup vs baseline: 1.5928x; 1.5928x over previous
//
#include <hip/hip_runtime.h>
#include <stdint.h>
#include <stddef.h>

// gcnmask: N=50000 nodes, DEG=16, F=128. Edges grouped by dst (dst = e/16) -> no atomics.
// R2: 8-wave blocks w/ N-split waves (occupancy 11%->~40%), bf16 x pre-convert, bf16 support.

#define NNODES 50000
#define DEG    16
#define FD     128
#define K2     256   // 2*F

typedef __bf16 bf16x8 __attribute__((ext_vector_type(8)));
typedef short  s16x8  __attribute__((ext_vector_type(8)));
typedef float  f32x4  __attribute__((ext_vector_type(4)));

__device__ __forceinline__ short f2bf_s(float f) {
    union { float f; uint32_t u; } v; v.f = f;
    uint32_t r = v.u + 0x7fffu + ((v.u >> 16) & 1u);   // RNE
    return (short)(r >> 16);
}
__device__ __forceinline__ float bf2f(short s) {
    union { uint32_t u; float f; } v; v.u = ((uint32_t)(uint16_t)s) << 16;
    return v.f;
}

// Pack weights_mask [256x128] and weight [128x128] into bf16 B-fragment order for
// mfma_f32_16x16x32_bf16: idx = ((kk*8+nt)*64 + q*16 + n15)*8 + (k&7).
// Also convert x [50000x128] fp32 -> bf16 row-major (8 elems/thread).
__global__ __launch_bounds__(256) void pack_k(const float* __restrict__ x,
                                              const float* __restrict__ wm,
                                              const float* __restrict__ w,
                                              short* __restrict__ bpack,
                                              short* __restrict__ wpack,
                                              short* __restrict__ xbf) {
    int tid = blockIdx.x * 256 + threadIdx.x;      // 3125*256 = 800000 = (50000*128)/8
    {
        const f32x4* s = reinterpret_cast<const f32x4*>(x) + (size_t)tid * 2;
        f32x4 a = s[0], b = s[1];
        s16x8 o;
        o[0]=f2bf_s(a.x); o[1]=f2bf_s(a.y); o[2]=f2bf_s(a.z); o[3]=f2bf_s(a.w);
        o[4]=f2bf_s(b.x); o[5]=f2bf_s(b.y); o[6]=f2bf_s(b.z); o[7]=f2bf_s(b.w);
        reinterpret_cast<s16x8*>(xbf)[tid] = o;
    }
    if (tid < K2 * FD) {
        int k = tid >> 7, n = tid & 127;
        int idx = (((k >> 5) * 8 + (n >> 4)) * 64 + ((k >> 3) & 3) * 16 + (n & 15)) * 8 + (k & 7);
        bpack[idx] = f2bf_s(wm[tid]);
    }
    if (tid < FD * FD) {
        int k = tid >> 7, n = tid & 127;
        int idx = (((k >> 5) * 8 + (n >> 4)) * 64 + ((k >> 3) & 3) * 16 + (n & 15)) * 8 + (k & 7);
        wpack[idx] = f2bf_s(w[tid]);
    }
}

// Block = 512 threads = 8 waves, 16 nodes. wave = wh*4 + wp:
//   wp (0..3) -> node group (4 nodes), wh (0..1) -> feature half (64 features).
// Phase 1: mask GEMM, acc[4 Mtiles][4 Ntiles]; A gathered bf16 (16 B/lane), B (Wm) from 64KB LDS.
// Phase 2: sigmoid + agg shuffle-reduce -> xn (aliased over Blds, stride 132).
// Phase 3: support[16x128] = xn @ weight; wave w does Ntile w; bf16 output.
__global__ __launch_bounds__(512, 4) void mask_agg_support_k(
    const float* __restrict__ x, const short* __restrict__ xbf,
    const int* __restrict__ esrc,
    const short* __restrict__ bpack, const short* __restrict__ wpack,
    short* __restrict__ support)
{
    __shared__ short Blds[K2 * FD];                 // 64 KB
    float* xn = reinterpret_cast<float*>(Blds);     // aliased after phase-1 barrier

    const int tid   = threadIdx.x;
    const int wave  = tid >> 6;
    const int lane  = tid & 63;
    const int q     = lane >> 4;
    const int m     = lane & 15;
    const int wp    = wave & 3;                     // node group
    const int wh    = wave >> 2;                    // feature half
    const int node0 = blockIdx.x * 16;
    const int wn0   = node0 + wp * 4;

    // stage packed Wm fragments into LDS (4096 uint4 / 512 threads = 8 iters)
    {
        const uint4* s = reinterpret_cast<const uint4*>(bpack);
        uint4* d = reinterpret_cast<uint4*>(Blds);
        #pragma unroll
        for (int i = 0; i < 8; ++i) d[tid + 512 * i] = s[tid + 512 * i];
    }

    int srcid[4];
    #pragma unroll
    for (int mt = 0; mt < 4; ++mt) srcid[mt] = esrc[(wn0 + mt) * DEG + m];

    __syncthreads();

    f32x4 acc[4][4];
    #pragma unroll
    for (int mt = 0; mt < 4; ++mt)
        #pragma unroll
        for (int nt = 0; nt < 4; ++nt)
            acc[mt][nt] = (f32x4){0.f, 0.f, 0.f, 0.f};

    #pragma unroll
    for (int kk = 0; kk < 8; ++kk) {
        bf16x8 af[4];
        #pragma unroll
        for (int mt = 0; mt < 4; ++mt) {
            // A layout: row = m, k = kk*32 + q*8 + j. Center rows (kk<4) are quad-broadcast.
            const int row = (kk < 4) ? (wn0 + mt) : srcid[mt];
            const short* rp = xbf + (size_t)row * FD + ((kk & 3) * 32 + q * 8);
            af[mt] = __builtin_bit_cast(bf16x8, *reinterpret_cast<const s16x8*>(rp));
        }
        #pragma unroll
        for (int nt = 0; nt < 4; ++nt) {
            const int ntile = wh * 4 + nt;
            s16x8 braw = *reinterpret_cast<const s16x8*>(Blds + ((size_t)(kk * 8 + ntile) * 64 + lane) * 8);
            bf16x8 bfr = __builtin_bit_cast(bf16x8, braw);
            #pragma unroll
            for (int mt = 0; mt < 4; ++mt)
                acc[mt][nt] = __builtin_amdgcn_mfma_f32_16x16x32_bf16(af[mt], bfr, acc[mt][nt], 0, 0, 0);
        }
    }

    __syncthreads();   // all waves done reading Blds; safe to overwrite with x_new

    // Phase 2: C/D layout: col = lane&15, row = q*4 + i (edge within node)
    #pragma unroll
    for (int mt = 0; mt < 4; ++mt) {
        const int node = wn0 + mt;
        const int s0 = __shfl(srcid[mt], q * 4 + 0);
        const int s1 = __shfl(srcid[mt], q * 4 + 1);
        const int s2 = __shfl(srcid[mt], q * 4 + 2);
        const int s3 = __shfl(srcid[mt], q * 4 + 3);
        #pragma unroll
        for (int nt = 0; nt < 4; ++nt) {
            const int f = (wh * 4 + nt) * 16 + m;
            f32x4 z = acc[mt][nt];
            float g0 = 1.f / (1.f + __expf(-z.x));
            float g1 = 1.f / (1.f + __expf(-z.y));
            float g2 = 1.f / (1.f + __expf(-z.z));
            float g3 = 1.f / (1.f + __expf(-z.w));
            float p = g0 * bf2f(xbf[(size_t)s0 * FD + f])
                    + g1 * bf2f(xbf[(size_t)s1 * FD + f])
                    + g2 * bf2f(xbf[(size_t)s2 * FD + f])
                    + g3 * bf2f(xbf[(size_t)s3 * FD + f]);
            p += __shfl_xor(p, 16);
            p += __shfl_xor(p, 32);
            if (q == 0) xn[(wp * 4 + mt) * 132 + f] = x[(size_t)node * FD + f] + p;
        }
    }
    __syncthreads();

    // Phase 3: support[16 x 128] = x_new @ weight. Wave w handles Ntile w.
    f32x4 sacc = (f32x4){0.f, 0.f, 0.f, 0.f};
    #pragma unroll
    for (int kk = 0; kk < 4; ++kk) {
        const float* p = &xn[m * 132 + kk * 32 + q * 8];
        bf16x8 a;
        a[0]=(__bf16)p[0]; a[1]=(__bf16)p[1]; a[2]=(__bf16)p[2]; a[3]=(__bf16)p[3];
        a[4]=(__bf16)p[4]; a[5]=(__bf16)p[5]; a[6]=(__bf16)p[6]; a[7]=(__bf16)p[7];
        s16x8 braw = *reinterpret_cast<const s16x8*>(wpack + ((size_t)(kk * 8 + wave) * 64 + lane) * 8);
        sacc = __builtin_amdgcn_mfma_f32_16x16x32_bf16(a, __builtin_bit_cast(bf16x8, braw), sacc, 0, 0, 0);
    }
    #pragma unroll
    for (int i = 0; i < 4; ++i)
        support[(size_t)(node0 + q * 4 + i) * FD + wave * 16 + m] = f2bf_s(sacc[i]);
}

// out[n][f] = bias[f] + sum_d adj[n*16+d] * support[src[n*16+d]][f]; n is wave-uniform.
__global__ __launch_bounds__(256) void final_agg_k(
    const short* __restrict__ support, const float* __restrict__ adj,
    const int* __restrict__ esrc, const float* __restrict__ bias,
    float* __restrict__ out)
{
    int tid = blockIdx.x * 256 + threadIdx.x;
    int n = tid >> 7;
    int f = tid & 127;
    float a = bias[f];
    int eb = n * DEG;
    #pragma unroll
    for (int d = 0; d < DEG; ++d) {
        int s = esrc[eb + d];
        a += adj[eb + d] * bf2f(support[(size_t)s * FD + f]);
    }
    out[tid] = a;
}

extern "C" void kernel_launch(void* const* d_in, const int* in_sizes, int n_in,
                              void* d_out, int out_size, void* d_ws, size_t ws_size,
                              hipStream_t stream) {
    const float* x      = (const float*)d_in[0];
    const float* weight = (const float*)d_in[1];
    const float* bias   = (const float*)d_in[2];
    const float* wm     = (const float*)d_in[3];
    const float* adj    = (const float*)d_in[4];
    const int*   esrc   = (const int*)d_in[5];
    // d_in[6] edge_dst unused: dst(e) = e/16 by construction.

    // ws: [0,64K) Wm bf16 | [64K,96K) weight bf16 | [96K,+12.8M) x bf16 | [+12.8M,+25.6M) support bf16
    short* bpack   = (short*)d_ws;
    short* wpack   = (short*)((char*)d_ws + 65536);
    short* xbf     = (short*)((char*)d_ws + 98304);
    short* support = (short*)((char*)d_ws + 98304 + (size_t)NNODES * FD * 2);
    float* out     = (float*)d_out;

    pack_k<<<3125, 256, 0, stream>>>(x, wm, weight, bpack, wpack, xbf);
    mask_agg_support_k<<<NNODES / 16, 512, 0, stream>>>(x, xbf, esrc, bpack, wpack, support);
    final_agg_k<<<(NNODES * FD) / 256, 256, 0, stream>>>(support, adj, esrc, bias, out);
}